// Round 2
// baseline (727.329 us; speedup 1.0000x reference)
//
#include <hip/hip_runtime.h>
#include <hip/hip_bf16.h>

// Conv: x(32,64,128,128) * w(128,64,3,3) VALID -> (32,128,126,126), ReLU,
// flattened to (32,128,15876).  Implicit GEMM per image:
//   C[128 kout][15876 sp] = W[128][576] . Xim2col[576][sp]
// W memory layout [k][c][3][3] is exactly row-major [128][576] (kdim = c*9+r*3+s).
// Block tile: 128 kout x 64 spatial (one output row, half-width), K-loop 18 x 32.
// bf16 MFMA 16x16x32, fp32 accum.

#define OUT0_SIZE (32 * 128 * 15876)
#define X_TOTAL   (32 * 64 * 128 * 128)
#define XMAX      (X_TOTAL - 1)

typedef __attribute__((ext_vector_type(8))) short short8v;   // 8 bf16 = 4 VGPRs
typedef __attribute__((ext_vector_type(4))) float float4v;   // MFMA C/D

static __device__ __forceinline__ unsigned bf16_rn(float f) {
  unsigned u = __float_as_uint(f);
  // round-to-nearest-even to bf16 (inputs are finite normals; no NaN path needed)
  u += 0x7FFFu + ((u >> 16) & 1u);
  return u >> 16;
}
static __device__ __forceinline__ unsigned pk2(float a, float b) {
  return bf16_rn(a) | (bf16_rn(b) << 16);
}

__global__ __launch_bounds__(256, 2) void conv3x3_relu_mfma(
    const float* __restrict__ x, const float* __restrict__ w,
    float* __restrict__ out) {
  // LDS rows padded to 40 bf16 (80 B) -> b128 frag reads stay 16B-aligned and
  // staging writes spread across all 32 banks.
  __shared__ __align__(16) short As[128 * 40];  // W chunk  [kout][32 kdim]
  __shared__ __align__(16) short Bs[64 * 40];   // X chunk  [tn]  [32 kdim]
  __shared__ int koff[576];                     // kdim -> c*16384 + r*128 + s

  const int tid  = threadIdx.x;
  const int wv   = tid >> 6;    // wave 0..3
  const int lane = tid & 63;
  const int l15  = lane & 15;
  const int quad = lane >> 4;

  const int owt = blockIdx.x;   // 0..1
  const int oh  = blockIdx.y;   // 0..125
  const int n   = blockIdx.z;   // 0..31
  const int ow0 = owt * 64;

  // one-time im2col offset table (avoids per-load div by 9)
  for (int i = tid; i < 576; i += 256) {
    int c  = i / 9;
    int rs = i - 9 * c;
    int r  = rs / 3;
    int s  = rs - 3 * r;
    koff[i] = c * 16384 + r * 128 + s;
  }
  __syncthreads();

  float4v acc[2][4];
#pragma unroll
  for (int i = 0; i < 2; ++i)
#pragma unroll
    for (int j = 0; j < 4; ++j)
      acc[i][j] = (float4v){0.f, 0.f, 0.f, 0.f};

  // per-thread bases
  const int xbase = n * 1048576 + oh * 128 + ow0 + lane;  // tn = lane
  const int akout = tid >> 1;   // A staging: 2 threads per kout row
  const int ahf   = tid & 1;

  for (int ks = 0; ks < 18; ++ks) {
    // ---- stage A: w[akout][ks*32 + ahf*16 .. +16] (contiguous fp32) ----
    const float4* ws = (const float4*)(w + akout * 576 + ks * 32 + ahf * 16);
    float4 f0 = ws[0], f1 = ws[1], f2 = ws[2], f3 = ws[3];

    // ---- stage B: row kdim = ks*32 + wv*8 + j, 64 contiguous cols (tn=lane)
    float bv[8];
#pragma unroll
    for (int j = 0; j < 8; ++j) {
      int kd  = ks * 32 + wv * 8 + j;
      int idx = xbase + koff[kd];       // LDS broadcast read (wave-uniform kd)
      idx = idx > XMAX ? XMAX : idx;    // clamp: only affects masked-out cols
      bv[j] = x[idx];
    }

    uint4 u0 = make_uint4(pk2(f0.x, f0.y), pk2(f0.z, f0.w),
                          pk2(f1.x, f1.y), pk2(f1.z, f1.w));
    uint4 u1 = make_uint4(pk2(f2.x, f2.y), pk2(f2.z, f2.w),
                          pk2(f3.x, f3.y), pk2(f3.z, f3.w));
    *(uint4*)&As[akout * 40 + ahf * 16]     = u0;
    *(uint4*)&As[akout * 40 + ahf * 16 + 8] = u1;

    uint4 ub = make_uint4(pk2(bv[0], bv[1]), pk2(bv[2], bv[3]),
                          pk2(bv[4], bv[5]), pk2(bv[6], bv[7]));
    *(uint4*)&Bs[lane * 40 + wv * 8] = ub;

    __syncthreads();

    // ---- fragments + MFMA: wave wv owns kout rows [wv*32, wv*32+32) ----
    short8v a0 = *(const short8v*)&As[(wv * 32 + l15) * 40 + quad * 8];
    short8v a1 = *(const short8v*)&As[(wv * 32 + 16 + l15) * 40 + quad * 8];
#pragma unroll
    for (int j = 0; j < 4; ++j) {
      short8v bb = *(const short8v*)&Bs[(j * 16 + l15) * 40 + quad * 8];
      acc[0][j] = __builtin_amdgcn_mfma_f32_16x16x32_bf16(a0, bb, acc[0][j], 0, 0, 0);
      acc[1][j] = __builtin_amdgcn_mfma_f32_16x16x32_bf16(a1, bb, acc[1][j], 0, 0, 0);
    }
    __syncthreads();
  }

  // ---- epilogue: ReLU + store.  C/D map: col=l15 (tn), row=quad*4+reg (kout)
  const int ob = (n * 128) * 15876 + oh * 126 + ow0;
#pragma unroll
  for (int i = 0; i < 2; ++i)
#pragma unroll
    for (int j = 0; j < 4; ++j)
#pragma unroll
      for (int r = 0; r < 4; ++r) {
        int kout = wv * 32 + i * 16 + quad * 4 + r;
        int tn   = j * 16 + l15;
        if (ow0 + tn < 126)
          out[ob + kout * 15876 + tn] = fmaxf(acc[i][j][r], 0.0f);
      }
}

// Output 1: concat(a,b) on last dim -> (1024, 2048), pure float4 copy.
__global__ void concat_kernel(const float* __restrict__ a,
                              const float* __restrict__ b,
                              float* __restrict__ o) {
  int i   = blockIdx.x * 256 + threadIdx.x;  // float4 index, 524288 total
  int row = i >> 9;                          // 512 float4 per out row
  int col = i & 511;
  const float4* src = (col < 256) ? (const float4*)a + (row << 8) + col
                                  : (const float4*)b + (row << 8) + (col - 256);
  ((float4*)o)[i] = *src;
}

extern "C" void kernel_launch(void* const* d_in, const int* in_sizes, int n_in,
                              void* d_out, int out_size, void* d_ws, size_t ws_size,
                              hipStream_t stream) {
  const float* x = (const float*)d_in[0];
  const float* w = (const float*)d_in[1];
  const float* a = (const float*)d_in[2];
  const float* b = (const float*)d_in[3];
  // d_in[4] = 'shape' (int64) — static, unused.

  float* out0 = (float*)d_out;
  float* out1 = out0 + OUT0_SIZE;

  dim3 grid(2, 126, 32);
  conv3x3_relu_mfma<<<grid, 256, 0, stream>>>(x, w, out0);
  concat_kernel<<<2048, 256, 0, stream>>>(a, b, out1);
}

// Round 3
// 459.165 us; speedup vs baseline: 1.5840x; 1.5840x over previous
//
#include <hip/hip_runtime.h>

// Conv x(32,64,128,128) * w(128,64,3,3) VALID + ReLU -> (32,128,126,126) flat.
// Per-tap implicit GEMM: for each of 9 taps (r,s): C += Wt[tap][128k][64c] . X[64c][sp]
// where X rows for all 3 s-taps of a given r come from ONE LDS staging of the raw
// x rows (s applied as a +s shift on the LDS read row). bf16 MFMA 16x16x32, fp32 acc.
// Tile: 128 kout x 128 sp (one full output row) per block, 4 waves.

#define OUT0_SIZE (32 * 128 * 15876)
#define X_TOTAL   (32 * 64 * 128 * 128)

typedef __attribute__((ext_vector_type(8))) short short8v;   // 8 bf16 (4 VGPRs)
typedef __attribute__((ext_vector_type(4))) float float4v;   // MFMA C/D

static __device__ __forceinline__ unsigned bf16_rn(float f) {
  unsigned u = __float_as_uint(f);
  u += 0x7FFFu + ((u >> 16) & 1u);   // RNE; inputs are finite normals
  return u >> 16;
}
static __device__ __forceinline__ unsigned pk2(float a, float b) {
  return bf16_rn(a) | (bf16_rn(b) << 16);
}

// Prepass: w[kout][c][r][s] fp32 -> wt[tap=r*3+s][kout][c] bf16 (147 KB, L2-resident)
__global__ void repack_w(const float* __restrict__ w, unsigned short* __restrict__ wt) {
  int o = blockIdx.x * 256 + threadIdx.x;       // 9*128*64 = 73728
  if (o >= 9 * 128 * 64) return;
  int tap  = o >> 13;
  int rem  = o & 8191;
  int kout = rem >> 6;
  int c    = rem & 63;
  wt[o] = (unsigned short)bf16_rn(w[kout * 576 + c * 9 + tap]);
}

__global__ __launch_bounds__(256, 2) void conv3x3_relu_mfma(
    const float* __restrict__ x, const unsigned short* __restrict__ wt,
    float* __restrict__ out) {
  // Bs[row=sp 0..131][64 c], 128 B rows, chunk-of-16B swizzled by pos = ch ^ ((row>>1)&7).
  __shared__ __align__(16) unsigned short Bs[132 * 64];   // 16.5 KB

  const int tid  = threadIdx.x;
  const int wv   = tid >> 6;
  const int lane = tid & 63;
  const int l15  = lane & 15;
  const int quad = lane >> 4;

  // XCD-aware oh swizzle: strip of 16 consecutive oh per (blockIdx.x % 8) so the
  // 3x cross-oh x-row reuse stays inside one XCD's L2.
  const int bx = blockIdx.x;                 // 0..127
  const int oh = (bx & 7) * 16 + (bx >> 3);
  if (oh >= 126) return;                     // 2 dead bx values
  const int n = blockIdx.y;

  float4v acc[2][8];
#pragma unroll
  for (int i = 0; i < 2; ++i)
#pragma unroll
    for (int j = 0; j < 8; ++j)
      acc[i][j] = (float4v){0.f, 0.f, 0.f, 0.f};

  // staging mapping: lane-> sp-pair (coalesced float2), wave -> c-octet
  const int spp = tid & 63;
  const int c8a = tid >> 6;                  // 0..3 (+4 on second half)
  const int xbase = n * 1048576 + oh * 128;

  // A-frag pipeline: load tap 0 before anything else
  short8v a_cur[2][2], a_nxt[2][2];
#pragma unroll
  for (int i = 0; i < 2; ++i)
#pragma unroll
    for (int kk = 0; kk < 2; ++kk)
      a_cur[i][kk] = *(const short8v*)(wt + (wv * 32 + i * 16 + l15) * 64 + kk * 32 + quad * 8);

  for (int r = 0; r < 3; ++r) {
    if (r) __syncthreads();                  // Bs reads of previous r done

    // ---- stage Bs: rows 0..127 (two c-octet rounds), perfectly coalesced ----
    const float* xp = x + xbase + r * 128 + 2 * spp;
#pragma unroll
    for (int half = 0; half < 2; ++half) {
      const int c8  = c8a + half * 4;
      const int pos = c8 ^ (spp & 7);
      float2 v[8];
#pragma unroll
      for (int j = 0; j < 8; ++j)
        v[j] = *(const float2*)(xp + (c8 * 8 + j) * 16384);
      uint4 lo = make_uint4(pk2(v[0].x, v[1].x), pk2(v[2].x, v[3].x),
                            pk2(v[4].x, v[5].x), pk2(v[6].x, v[7].x));
      uint4 hi = make_uint4(pk2(v[0].y, v[1].y), pk2(v[2].y, v[3].y),
                            pk2(v[4].y, v[5].y), pk2(v[6].y, v[7].y));
      *(uint4*)&Bs[(2 * spp)     * 64 + pos * 8] = lo;
      *(uint4*)&Bs[(2 * spp + 1) * 64 + pos * 8] = hi;
    }
    // rows 128..131 (feed only masked sp>=126 outputs; clamp keeps reads in-bounds)
    if (tid < 16) {
      const int sppx = 64 + (tid >> 3);
      const int c8   = tid & 7;
      const int pos  = c8 ^ (sppx & 7);
      float2 v[8];
#pragma unroll
      for (int j = 0; j < 8; ++j) {
        int idx = xbase + r * 128 + 2 * sppx + (c8 * 8 + j) * 16384;
        idx = idx > (X_TOTAL - 2) ? (X_TOTAL - 2) : idx;
        v[j] = *(const float2*)(x + idx);
      }
      uint4 lo = make_uint4(pk2(v[0].x, v[1].x), pk2(v[2].x, v[3].x),
                            pk2(v[4].x, v[5].x), pk2(v[6].x, v[7].x));
      uint4 hi = make_uint4(pk2(v[0].y, v[1].y), pk2(v[2].y, v[3].y),
                            pk2(v[4].y, v[5].y), pk2(v[6].y, v[7].y));
      *(uint4*)&Bs[(2 * sppx)     * 64 + pos * 8] = lo;
      *(uint4*)&Bs[(2 * sppx + 1) * 64 + pos * 8] = hi;
    }
    __syncthreads();

    // ---- 3 taps off one staging; A for next tap prefetched during compute ----
#pragma unroll
    for (int s = 0; s < 3; ++s) {
      const int ntap = r * 3 + s + 1;        // next tap to prefetch
      if (ntap < 9) {
#pragma unroll
        for (int i = 0; i < 2; ++i)
#pragma unroll
          for (int kk = 0; kk < 2; ++kk)
            a_nxt[i][kk] = *(const short8v*)(wt + ntap * 8192 +
                (wv * 32 + i * 16 + l15) * 64 + kk * 32 + quad * 8);
      }
#pragma unroll
      for (int j = 0; j < 8; ++j) {
        const int row = j * 16 + l15 + s;
        const int sw  = (row >> 1) & 7;
#pragma unroll
        for (int kk = 0; kk < 2; ++kk) {
          const int pos = (kk * 4 + quad) ^ sw;
          short8v b = *(const short8v*)&Bs[row * 64 + pos * 8];
          acc[0][j] = __builtin_amdgcn_mfma_f32_16x16x32_bf16(a_cur[0][kk], b, acc[0][j], 0, 0, 0);
          acc[1][j] = __builtin_amdgcn_mfma_f32_16x16x32_bf16(a_cur[1][kk], b, acc[1][j], 0, 0, 0);
        }
      }
#pragma unroll
      for (int i = 0; i < 2; ++i)
#pragma unroll
        for (int kk = 0; kk < 2; ++kk)
          a_cur[i][kk] = a_nxt[i][kk];
    }
  }

  // ---- epilogue: ReLU + store. C/D: col=l15 (sp), row=quad*4+reg (kout) ----
  const int ob = n * 128 * 15876 + oh * 126;
#pragma unroll
  for (int i = 0; i < 2; ++i)
#pragma unroll
    for (int j = 0; j < 8; ++j) {
      const int sp = j * 16 + l15;
      if (sp < 126) {
#pragma unroll
        for (int reg = 0; reg < 4; ++reg) {
          const int kout = wv * 32 + i * 16 + quad * 4 + reg;
          out[ob + kout * 15876 + sp] = fmaxf(acc[i][j][reg], 0.0f);
        }
      }
    }
}

// Output 1: concat(a,b) last dim -> (1024, 2048), float4 copy.
__global__ void concat_kernel(const float* __restrict__ a,
                              const float* __restrict__ b,
                              float* __restrict__ o) {
  int i   = blockIdx.x * 256 + threadIdx.x;  // 524288 float4
  int row = i >> 9;
  int col = i & 511;
  const float4* src = (col < 256) ? (const float4*)a + (row << 8) + col
                                  : (const float4*)b + (row << 8) + (col - 256);
  ((float4*)o)[i] = *src;
}

extern "C" void kernel_launch(void* const* d_in, const int* in_sizes, int n_in,
                              void* d_out, int out_size, void* d_ws, size_t ws_size,
                              hipStream_t stream) {
  const float* x = (const float*)d_in[0];
  const float* w = (const float*)d_in[1];
  const float* a = (const float*)d_in[2];
  const float* b = (const float*)d_in[3];

  float* out0 = (float*)d_out;
  float* out1 = out0 + OUT0_SIZE;
  unsigned short* wt = (unsigned short*)d_ws;   // 147456 B

  repack_w<<<288, 256, 0, stream>>>(w, wt);
  dim3 grid(128, 32);
  conv3x3_relu_mfma<<<grid, 256, 0, stream>>>(x, wt, out0);
  concat_kernel<<<2048, 256, 0, stream>>>(a, b, out1);
}